// Round 6
// baseline (102.395 us; speedup 1.0000x reference)
//
#include <hip/hip_runtime.h>

#define MARGIN 0.0625f

// Problem sizes (fixed by the reference)
#define P 4096        // 64*64 query points
#define M 100000      // means
#define G 500         // mean-chunks: 500*200 = 100000 exactly
#define CHUNK 200     // means per chunk
#define NQUAD (CHUNK / 4)   // 50 float4 groups per LDS array
#define QS 4          // query slabs
#define R 4           // queries per thread (256*R*QS = 4096)
#define NCH 2         // chunks per block -> grid (G/NCH, QS) = 1000 blocks
#define GB (G / NCH)  // 250
#define NCOPY 32      // atomic spread: pmin[NCOPY][P]

typedef float float4v __attribute__((ext_vector_type(4)));

// ws layout (bytes):
//   pmin[NCOPY][P] (uint, float-bits running min) @ 0  -- 512 KB, L2-resident
#define WS_PMIN_OFF 0

// NOTE (measured r4->r5): v_pk_fma_f32 is HALF-RATE on gfx950 -- fp32 peak
// 157.3 TF is the scalar v_fma_f32 rate (VALU busy time identical for
// scalarized and packed variants). Scalar fma + v_min3 is the optimal
// encoding: 3 fma + 0.5 min3 per mean = 3.5 instr -> 18.2 us chip floor.
static __device__ __forceinline__ float min3f(float a, float b, float c) {
    float d;
    asm("v_min3_f32 %0, %1, %2, %3" : "=v"(d) : "v"(a), "v"(b), "v"(c));
    return d;
}

// ---------------------------------------------------------------------------
// Fused kernel: each block owns NCH=2 consecutive 200-mean chunks and one
// query slab. Chunk B's global loads issue BEFORE scan A (latency hides
// under 2800 cycles of FMA), land in LDS buffer 1 after scan A. Query
// transform computed once per block (was once per chunk); single epilogue
// atomic pass with the min carried across both chunks (halves the atomic
// burst). All stored d2 are fmax(...,0) >= +0.0 so uint order == float
// order.
// ---------------------------------------------------------------------------
__global__ __launch_bounds__(256, 4) void nn_kernel(
    const float* __restrict__ outputs,   // [P*3]
    const float* __restrict__ c2ws,      // [64*16]
    const float* __restrict__ scales,    // [64]
    const float* __restrict__ means,     // [M*3] raw
    unsigned int* __restrict__ pmin)     // [NCOPY*P] float-bits, init 0xFF..
{
    const int t  = threadIdx.x;
    const int gb = blockIdx.x;
    const int qs = blockIdx.y;
    const int pbase = qs * (P / QS);
    const int mbase = gb * NCH * CHUNK;

    // Double-buffered SoA chunks in LDS as float4 groups -> ds_read_b128 at
    // wave-uniform addresses (broadcast, conflict-free). 6.4 KB total.
    __shared__ float4v lxs[2][NQUAD], lys[2][NQUAD], lzs[2][NQUAD], lms[2][NQUAD];

    // ---- prep chunk 0: transform 200 raw means into LDS buffer 0 ----
    if (t < CHUNK) {
        const float* mp = means + 3 * (mbase + t);
        float x = mp[0], y = mp[1], z = mp[2];
        ((float*)lxs[0])[t] = -2.0f * x;
        ((float*)lys[0])[t] = -2.0f * y;
        ((float*)lzs[0])[t] = -2.0f * z;
        ((float*)lms[0])[t] = fmaf(x, x, fmaf(y, y, z * z));
    }

    // ---- queries: computed once per block ----
    float q0[R], q1[R], q2[R], qq[R], mn[R];
#pragma unroll
    for (int i = 0; i < R; ++i) {
        int p = pbase + i * 256 + t;
        int b = p >> 6;
        float s  = scales[b];
        float o0 = outputs[3 * p + 0];
        float o1 = outputs[3 * p + 1];
        float o2 = outputs[3 * p + 2];
        const float* cw = c2ws + b * 16;
        q0[i] = fmaf(s, fmaf(cw[0],  o0, fmaf(cw[1],  o1, cw[2]  * o2)), cw[3]);
        q1[i] = fmaf(s, fmaf(cw[4],  o0, fmaf(cw[5],  o1, cw[6]  * o2)), cw[7]);
        q2[i] = fmaf(s, fmaf(cw[8],  o0, fmaf(cw[9],  o1, cw[10] * o2)), cw[11]);
        qq[i] = fmaf(q0[i], q0[i], fmaf(q1[i], q1[i], q2[i] * q2[i]));
        mn[i] = 1e30f;
    }

    __syncthreads();

    // ---- issue-early: chunk 1's global loads go out now; the s_waitcnt
    // lands after scan 0 (~2800 cycles of cover). T14 pattern.
    float nx_ = 0.0f, ny_ = 0.0f, nz_ = 0.0f;
    if (t < CHUNK) {
        const float* mp = means + 3 * (mbase + CHUNK + t);
        nx_ = mp[0]; ny_ = mp[1]; nz_ = mp[2];
    }

    // ---- scan one 50-quad chunk from LDS buffer b, software-pipelined ----
#define SCAN(b)                                                               \
    do {                                                                      \
        float4v cx = lxs[b][0], cy = lys[b][0], cz = lzs[b][0], cm = lms[b][0];\
        _Pragma("unroll 2")                                                   \
        for (int j = 0; j < NQUAD; ++j) {                                     \
            int jn = (j + 1 < NQUAD) ? j + 1 : 0;                             \
            float4v nx = lxs[b][jn], ny = lys[b][jn],                         \
                    nz = lzs[b][jn], nm = lms[b][jn];                         \
            _Pragma("unroll")                                                 \
            for (int i = 0; i < R; ++i) {                                     \
                float t0 = fmaf(q2[i], cz[0], fmaf(q1[i], cy[0],              \
                           fmaf(q0[i], cx[0], cm[0])));                       \
                float t1 = fmaf(q2[i], cz[1], fmaf(q1[i], cy[1],              \
                           fmaf(q0[i], cx[1], cm[1])));                       \
                float t2 = fmaf(q2[i], cz[2], fmaf(q1[i], cy[2],              \
                           fmaf(q0[i], cx[2], cm[2])));                       \
                float t3 = fmaf(q2[i], cz[3], fmaf(q1[i], cy[3],              \
                           fmaf(q0[i], cx[3], cm[3])));                       \
                mn[i] = min3f(t0, t1, mn[i]);                                 \
                mn[i] = min3f(t2, t3, mn[i]);                                 \
            }                                                                 \
            cx = nx; cy = ny; cz = nz; cm = nm;                               \
        }                                                                     \
    } while (0)

    SCAN(0);

    // ---- write chunk 1 into LDS buffer 1 (loads already in flight) ----
    if (t < CHUNK) {
        ((float*)lxs[1])[t] = -2.0f * nx_;
        ((float*)lys[1])[t] = -2.0f * ny_;
        ((float*)lzs[1])[t] = -2.0f * nz_;
        ((float*)lms[1])[t] = fmaf(nx_, nx_, fmaf(ny_, ny_, nz_ * nz_));
    }
    __syncthreads();

    SCAN(1);
#undef SCAN

    // ---- single epilogue over both chunks: fold qq, clamp, filtered
    // atomicMin into this block's spread copy. Filter read may be stale
    // (monotonically decreasing target) so skipping is always safe; the
    // atomic is authoritative.
    unsigned int* __restrict__ pm = pmin + (gb & (NCOPY - 1)) * P;
#pragma unroll
    for (int i = 0; i < R; ++i) {
        int p = pbase + i * 256 + t;
        float d = fmaxf(qq[i] + mn[i], 0.0f);
        unsigned int bits = __float_as_uint(d);
        if (bits < pm[p]) atomicMin(&pm[p], bits);
    }
}

// ---------------------------------------------------------------------------
// Kernel 2: loss. Fold the 32 spread copies (512 KB, L2-hot), then
// relu(MARGIN-d)/P, wave-reduce, one atomicAdd per block (16 blocks).
// ---------------------------------------------------------------------------
__global__ __launch_bounds__(256) void finish_kernel(
    const unsigned int* __restrict__ pmin,
    float* __restrict__ out)
{
    const int t = threadIdx.x;
    const int q = blockIdx.x * 256 + t;

    unsigned int mb = 0xFFFFFFFFu;
#pragma unroll
    for (int c = 0; c < NCOPY; ++c)
        mb = min(mb, pmin[c * P + q]);

    float m = __uint_as_float(mb);
    float v = fmaxf(MARGIN - m, 0.0f) * (1.0f / (float)P);

#pragma unroll
    for (int off = 32; off > 0; off >>= 1)
        v += __shfl_down(v, off, 64);

    __shared__ float lds[4];
    int wid = t >> 6;
    if ((t & 63) == 0) lds[wid] = v;
    __syncthreads();
    if (t == 0)
        atomicAdd(out, lds[0] + lds[1] + lds[2] + lds[3]);
}

extern "C" void kernel_launch(void* const* d_in, const int* in_sizes, int n_in,
                              void* d_out, int out_size, void* d_ws, size_t ws_size,
                              hipStream_t stream) {
    const float* outputs = (const float*)d_in[0];  // (64,64,3)
    const float* c2ws    = (const float*)d_in[1];  // (64,4,4)
    const float* scales  = (const float*)d_in[2];  // (64,)
    const float* means   = (const float*)d_in[3];  // (100000,3)

    unsigned int* pmin = (unsigned int*)((char*)d_ws + WS_PMIN_OFF);
    float* out = (float*)d_out;

    // 0xFF bytes -> 0xFFFFFFFF = uint-max sentinel (beats any d2 bit pattern).
    hipMemsetAsync(pmin, 0xFF, NCOPY * P * sizeof(unsigned int), stream);
    hipMemsetAsync(out, 0, sizeof(float), stream);

    nn_kernel<<<dim3(GB, QS), 256, 0, stream>>>(outputs, c2ws, scales, means, pmin);
    finish_kernel<<<P / 256, 256, 0, stream>>>(pmin, out);
}